// Round 7
// baseline (129.329 us; speedup 1.0000x reference)
//
#include <hip/hip_runtime.h>

#define S    512
#define OUT  512
#define NB   8
#define CB   32
#define TRW  16                      // rows per wave
#define NBLK (NB * CB * 8)           // 256 planes * 8 blocks/plane = 2048

// ---------------------------------------------------------------------------
// Kernel 1 (v3, unchanged): wave-per-row inverse-CDF coords, register-resident.
// ---------------------------------------------------------------------------
__global__ __launch_bounds__(64) void coords_kernel(
    const float* __restrict__ attx, const float* __restrict__ atty,
    int2* __restrict__ coords)               // [2][8][512]
{
  __shared__ double sc[S];
  const int lane = threadIdx.x;              // 0..63
  const int n    = blockIdx.x & 7;
  const int axis = blockIdx.x >> 3;
  const float* att = (axis == 0 ? attx : atty) + n * S;

  double a[8];
#pragma unroll
  for (int k = 0; k < 8; ++k) a[k] = (double)att[lane * 8 + k];

  double tot = 0.0;
#pragma unroll
  for (int k = 0; k < 8; ++k) tot += a[k];
#pragma unroll
  for (int off = 32; off > 0; off >>= 1) tot += __shfl_xor(tot, off);

#pragma unroll
  for (int k = 0; k < 8; ++k) a[k] = a[k] / tot * (double)OUT;
  const double thr = (double)(4 * OUT) / (double)S;   // = 4.0

  for (int it = 0; it < 5; ++it) {
    double s = 0.0;
#pragma unroll
    for (int k = 0; k < 8; ++k) { a[k] = a[k] < thr ? a[k] : thr; s += a[k]; }
#pragma unroll
    for (int off = 32; off > 0; off >>= 1) s += __shfl_xor(s, off);
    const double corr = ((double)OUT - s) / (double)S;
#pragma unroll
    for (int k = 0; k < 8; ++k) a[k] += corr;
  }

  double p[8]; double run = 0.0;
#pragma unroll
  for (int k = 0; k < 8; ++k) { run += a[k]; p[k] = run; }
  double v = run;
#pragma unroll
  for (int off = 1; off < 64; off <<= 1) {
    double t = __shfl_up(v, off);
    if (lane >= off) v += t;
  }
  const double excl = v - run;
#pragma unroll
  for (int k = 0; k < 8; ++k) sc[lane * 8 + k] = excl + p[k];
  __syncthreads();

  const double step = sc[S - 1] / (double)OUT;

#pragma unroll
  for (int k = 0; k < 8; ++k) {
    const int ox = lane * 8 + k;
    const double tgt = step * (double)(ox + 1);

    int lo = 0, hi = S;
    while (lo < hi) {
      int mid = (lo + hi) >> 1;
      if (sc[mid] < tgt) lo = mid + 1; else hi = mid;
    }
    int j = lo < S - 1 ? lo : S - 1;

    double right = sc[j];
    double left  = (j > 0) ? sc[j - 1] : 0.0;
    double denom = right - left;
    if (denom < 1e-8) denom = 1e-8;
    double frac = (tgt - left) / denom;
    frac = frac < 0.0 ? 0.0 : (frac > 1.0 ? 1.0 : frac);

    double pp  = ((double)j + frac) / (double)S * (double)(S - 1);
    double p0f = floor(pp);
    double w   = pp - p0f;
    int i0 = (int)p0f;
    i0 = i0 < 0 ? 0 : (i0 > S - 1 ? S - 1 : i0);

    coords[(axis * NB + n) * S + ox] = make_int2(i0, __float_as_int((float)w));
  }
}

// ---------------------------------------------------------------------------
// Kernel 2 (v7): sliding-window Cx reuse, barrier-free, wave-private.
// i0y is monotone per wave, so the x-gathered rows (Cx) live in registers:
//   advance +0: reuse CxA,CxB (no loads, no LDS)
//   advance +1: CxA <- CxB (8 movs); load+stage+gather ONE new row
//   jump >= 2 : load+stage+gather both rows
// Cuts logical global reads ~40%, LDS traffic ~2x, x-lerp VALU ~2x vs v6.
// LDS gather uses b32 layout (monotone ix ~ 2 lanes/bank). ~60 VGPR target.
// ---------------------------------------------------------------------------
__global__ __launch_bounds__(256) void sample_kernel(
    const float* __restrict__ data, const int2* __restrict__ coords,
    float* __restrict__ out)
{
  __shared__ float bufA_[4][S + 1];
  __shared__ float bufB_[4][S + 1];

  int b = (int)blockIdx.x;
  b = (b & 7) * (NBLK / 8) + (b >> 3);       // bijective XCD swizzle
  const int plane = b >> 3;                  // n*CB + c
  const int bip   = b & 7;
  const int n     = plane >> 5;

  const int tid  = threadIdx.x;
  const int wv   = tid >> 6;
  const int lane = tid & 63;
  const int oy0  = bip * 64 + wv * TRW;

  const float* __restrict__ pl = data + (size_t)plane * (S * S);
  float* __restrict__       po = out  + (size_t)plane * (S * S);

  // hoisted x coords: lane handles ox = lane + 64k
  int   ix[8];
  float wx[8];
#pragma unroll
  for (int k = 0; k < 8; ++k) {
    const int2 cx = coords[n * S + lane + 64 * k];
    ix[k] = cx.x;
    wx[k] = __int_as_float(cx.y);
  }

  float* bufA = bufA_[wv];
  float* bufB = bufB_[wv];
  const int2* __restrict__ cyp = coords + (NB + n) * S + oy0;

  float CxA[8], CxB[8];
  int curA = -1000;                          // forces jump path at r=0

  for (int r = 0; r < TRW; ++r) {
    const int2 cy = cyp[r];                  // wave-uniform
    const int   a  = cy.x;
    const float wy = __int_as_float(cy.y);

    if (a != curA) {
      const int rowB = (a + 1 < S) ? a + 1 : S - 1;
      if (a == curA + 1) {
        // +1 advance: old B row becomes new A row — shift registers
#pragma unroll
        for (int k = 0; k < 8; ++k) CxA[k] = CxB[k];
        const float4* RB = (const float4*)(pl + (size_t)rowB * S);
        const float4 p0 = RB[lane];
        const float4 p1 = RB[lane + 64];
        ((float4*)bufB)[lane]      = p0;
        ((float4*)bufB)[lane + 64] = p1;
        if (lane == 63) bufB[S] = p1.w;      // pad: clamp to last element
#pragma unroll
        for (int k = 0; k < 8; ++k) {
          const float x0 = bufB[ix[k]];
          const float x1 = bufB[ix[k] + 1];
          CxB[k] = x0 + wx[k] * (x1 - x0);
        }
      } else {
        // jump: load + stage + gather both rows (loads issue back-to-back)
        const float4* RA = (const float4*)(pl + (size_t)a    * S);
        const float4* RB = (const float4*)(pl + (size_t)rowB * S);
        const float4 q0 = RA[lane];
        const float4 q1 = RA[lane + 64];
        const float4 p0 = RB[lane];
        const float4 p1 = RB[lane + 64];
        ((float4*)bufA)[lane]      = q0;
        ((float4*)bufA)[lane + 64] = q1;
        ((float4*)bufB)[lane]      = p0;
        ((float4*)bufB)[lane + 64] = p1;
        if (lane == 63) { bufA[S] = q1.w; bufB[S] = p1.w; }
#pragma unroll
        for (int k = 0; k < 8; ++k) {
          const float x0 = bufA[ix[k]];
          const float x1 = bufA[ix[k] + 1];
          CxA[k] = x0 + wx[k] * (x1 - x0);
        }
#pragma unroll
        for (int k = 0; k < 8; ++k) {
          const float x0 = bufB[ix[k]];
          const float x1 = bufB[ix[k] + 1];
          CxB[k] = x0 + wx[k] * (x1 - x0);
        }
      }
      curA = a;
    }

    // y-lerp + coalesced stores (wave covers the full 2 KB row)
    float* orow = po + (size_t)(oy0 + r) * OUT;
#pragma unroll
    for (int k = 0; k < 8; ++k)
      orow[lane + 64 * k] = CxA[k] + wy * (CxB[k] - CxA[k]);
  }
}

extern "C" void kernel_launch(void* const* d_in, const int* in_sizes, int n_in,
                              void* d_out, int out_size, void* d_ws, size_t ws_size,
                              hipStream_t stream) {
  const float* data = (const float*)d_in[0];
  const float* attx = (const float*)d_in[1];
  const float* atty = (const float*)d_in[2];
  float* out = (float*)d_out;

  // Workspace: int2 coords[2][8][512]  (x coords then y coords), 64 KB
  int2* coords = (int2*)d_ws;

  coords_kernel<<<16, 64, 0, stream>>>(attx, atty, coords);

  sample_kernel<<<NBLK, 256, 0, stream>>>(data, coords, out);
}

// Round 8
// 104.683 us; speedup vs baseline: 1.2354x; 1.2354x over previous
//
#include <hip/hip_runtime.h>

#define S    512
#define OUT  512
#define NB   8
#define CB   32
#define TRW  16                      // rows per wave
#define NBLK (NB * CB * 8)           // 256 planes * 8 blocks/plane = 2048

// ---------------------------------------------------------------------------
// Kernel 1 (v3, unchanged): wave-per-row inverse-CDF coords, register-resident.
// ---------------------------------------------------------------------------
__global__ __launch_bounds__(64) void coords_kernel(
    const float* __restrict__ attx, const float* __restrict__ atty,
    int2* __restrict__ coords)               // [2][8][512]
{
  __shared__ double sc[S];
  const int lane = threadIdx.x;              // 0..63
  const int n    = blockIdx.x & 7;
  const int axis = blockIdx.x >> 3;
  const float* att = (axis == 0 ? attx : atty) + n * S;

  double a[8];
#pragma unroll
  for (int k = 0; k < 8; ++k) a[k] = (double)att[lane * 8 + k];

  double tot = 0.0;
#pragma unroll
  for (int k = 0; k < 8; ++k) tot += a[k];
#pragma unroll
  for (int off = 32; off > 0; off >>= 1) tot += __shfl_xor(tot, off);

#pragma unroll
  for (int k = 0; k < 8; ++k) a[k] = a[k] / tot * (double)OUT;
  const double thr = (double)(4 * OUT) / (double)S;   // = 4.0

  for (int it = 0; it < 5; ++it) {
    double s = 0.0;
#pragma unroll
    for (int k = 0; k < 8; ++k) { a[k] = a[k] < thr ? a[k] : thr; s += a[k]; }
#pragma unroll
    for (int off = 32; off > 0; off >>= 1) s += __shfl_xor(s, off);
    const double corr = ((double)OUT - s) / (double)S;
#pragma unroll
    for (int k = 0; k < 8; ++k) a[k] += corr;
  }

  double p[8]; double run = 0.0;
#pragma unroll
  for (int k = 0; k < 8; ++k) { run += a[k]; p[k] = run; }
  double v = run;
#pragma unroll
  for (int off = 1; off < 64; off <<= 1) {
    double t = __shfl_up(v, off);
    if (lane >= off) v += t;
  }
  const double excl = v - run;
#pragma unroll
  for (int k = 0; k < 8; ++k) sc[lane * 8 + k] = excl + p[k];
  __syncthreads();

  const double step = sc[S - 1] / (double)OUT;

#pragma unroll
  for (int k = 0; k < 8; ++k) {
    const int ox = lane * 8 + k;
    const double tgt = step * (double)(ox + 1);

    int lo = 0, hi = S;
    while (lo < hi) {
      int mid = (lo + hi) >> 1;
      if (sc[mid] < tgt) lo = mid + 1; else hi = mid;
    }
    int j = lo < S - 1 ? lo : S - 1;

    double right = sc[j];
    double left  = (j > 0) ? sc[j - 1] : 0.0;
    double denom = right - left;
    if (denom < 1e-8) denom = 1e-8;
    double frac = (tgt - left) / denom;
    frac = frac < 0.0 ? 0.0 : (frac > 1.0 ? 1.0 : frac);

    double pp  = ((double)j + frac) / (double)S * (double)(S - 1);
    double p0f = floor(pp);
    double w   = pp - p0f;
    int i0 = (int)p0f;
    i0 = i0 < 0 ? 0 : (i0 > S - 1 ? S - 1 : i0);

    coords[(axis * NB + n) * S + ox] = make_int2(i0, __float_as_int((float)w));
  }
}

// ---------------------------------------------------------------------------
// Kernel 2 (v8 = v7 + nontemporal output stores): sliding-window Cx reuse,
// barrier-free, wave-private. Output is write-once/never-re-read, so `nt`
// stores keep the 268 MB write stream from thrashing the input out of the
// 256 MB Infinity Cache (observed: ~128 MB/replay of input re-fetched).
// ---------------------------------------------------------------------------
__global__ __launch_bounds__(256) void sample_kernel(
    const float* __restrict__ data, const int2* __restrict__ coords,
    float* __restrict__ out)
{
  __shared__ float bufA_[4][S + 1];
  __shared__ float bufB_[4][S + 1];

  int b = (int)blockIdx.x;
  b = (b & 7) * (NBLK / 8) + (b >> 3);       // bijective XCD swizzle
  const int plane = b >> 3;                  // n*CB + c
  const int bip   = b & 7;
  const int n     = plane >> 5;

  const int tid  = threadIdx.x;
  const int wv   = tid >> 6;
  const int lane = tid & 63;
  const int oy0  = bip * 64 + wv * TRW;

  const float* __restrict__ pl = data + (size_t)plane * (S * S);
  float* __restrict__       po = out  + (size_t)plane * (S * S);

  // hoisted x coords: lane handles ox = lane + 64k
  int   ix[8];
  float wx[8];
#pragma unroll
  for (int k = 0; k < 8; ++k) {
    const int2 cx = coords[n * S + lane + 64 * k];
    ix[k] = cx.x;
    wx[k] = __int_as_float(cx.y);
  }

  float* bufA = bufA_[wv];
  float* bufB = bufB_[wv];
  const int2* __restrict__ cyp = coords + (NB + n) * S + oy0;

  float CxA[8], CxB[8];
  int curA = -1000;                          // forces jump path at r=0

  for (int r = 0; r < TRW; ++r) {
    const int2 cy = cyp[r];                  // wave-uniform
    const int   a  = cy.x;
    const float wy = __int_as_float(cy.y);

    if (a != curA) {
      const int rowB = (a + 1 < S) ? a + 1 : S - 1;
      if (a == curA + 1) {
        // +1 advance: old B row becomes new A row — shift registers
#pragma unroll
        for (int k = 0; k < 8; ++k) CxA[k] = CxB[k];
        const float4* RB = (const float4*)(pl + (size_t)rowB * S);
        const float4 p0 = RB[lane];
        const float4 p1 = RB[lane + 64];
        ((float4*)bufB)[lane]      = p0;
        ((float4*)bufB)[lane + 64] = p1;
        if (lane == 63) bufB[S] = p1.w;      // pad: clamp to last element
#pragma unroll
        for (int k = 0; k < 8; ++k) {
          const float x0 = bufB[ix[k]];
          const float x1 = bufB[ix[k] + 1];
          CxB[k] = x0 + wx[k] * (x1 - x0);
        }
      } else {
        // jump: load + stage + gather both rows (loads issue back-to-back)
        const float4* RA = (const float4*)(pl + (size_t)a    * S);
        const float4* RB = (const float4*)(pl + (size_t)rowB * S);
        const float4 q0 = RA[lane];
        const float4 q1 = RA[lane + 64];
        const float4 p0 = RB[lane];
        const float4 p1 = RB[lane + 64];
        ((float4*)bufA)[lane]      = q0;
        ((float4*)bufA)[lane + 64] = q1;
        ((float4*)bufB)[lane]      = p0;
        ((float4*)bufB)[lane + 64] = p1;
        if (lane == 63) { bufA[S] = q1.w; bufB[S] = p1.w; }
#pragma unroll
        for (int k = 0; k < 8; ++k) {
          const float x0 = bufA[ix[k]];
          const float x1 = bufA[ix[k] + 1];
          CxA[k] = x0 + wx[k] * (x1 - x0);
        }
#pragma unroll
        for (int k = 0; k < 8; ++k) {
          const float x0 = bufB[ix[k]];
          const float x1 = bufB[ix[k] + 1];
          CxB[k] = x0 + wx[k] * (x1 - x0);
        }
      }
      curA = a;
    }

    // y-lerp + coalesced NONTEMPORAL stores (wave covers the full 2 KB row)
    float* orow = po + (size_t)(oy0 + r) * OUT;
#pragma unroll
    for (int k = 0; k < 8; ++k)
      __builtin_nontemporal_store(CxA[k] + wy * (CxB[k] - CxA[k]),
                                  orow + lane + 64 * k);
  }
}

extern "C" void kernel_launch(void* const* d_in, const int* in_sizes, int n_in,
                              void* d_out, int out_size, void* d_ws, size_t ws_size,
                              hipStream_t stream) {
  const float* data = (const float*)d_in[0];
  const float* attx = (const float*)d_in[1];
  const float* atty = (const float*)d_in[2];
  float* out = (float*)d_out;

  // Workspace: int2 coords[2][8][512]  (x coords then y coords), 64 KB
  int2* coords = (int2*)d_ws;

  coords_kernel<<<16, 64, 0, stream>>>(attx, atty, coords);

  sample_kernel<<<NBLK, 256, 0, stream>>>(data, coords, out);
}